// Round 1
// baseline (474.779 us; speedup 1.0000x reference)
//
#include <hip/hip_runtime.h>
#include <stdint.h>

// Problem constants (fixed by the reference).
#define VOCAB_P1 100001
#define EMB_DIM  128
#define BATCH    256
#define NNZ_Q    2048
#define NNZ_D    262144

#define NPAD 112   // j (hidden=100) padded to 7 tiles of 16
#define KDIM 128   // emb dim = MFMA K total
#define ROWP 136   // LDS row stride in shorts: 128 + 8 pad to break bank aliasing
#define EPB  64    // entries per block

typedef __attribute__((ext_vector_type(8))) short  short8;   // 8 bf16 = 4 VGPRs
typedef __attribute__((ext_vector_type(4))) float  float4v;  // MFMA acc

__device__ __forceinline__ unsigned short f2bf(float f) {
    // round-to-nearest-even float -> bf16 bits (values here are all normal)
    union { float f; unsigned u; } v; v.f = f;
    unsigned u = v.u;
    u += 0x7fffu + ((u >> 16) & 1u);
    return (unsigned short)(u >> 16);
}

// Fused: gather emb rows -> bf16 LDS, MFMA GEMM vs W1^T, relu+b1, dot W2,
// relu+b2, * d_freqs, scatter-add into dense d + rowsum + colsum.
__global__ __launch_bounds__(256) void mlp_scatter_kernel(
    const int* __restrict__ d_rows, const int* __restrict__ d_cols,
    const float* __restrict__ d_freqs, const float* __restrict__ emb,
    const float* __restrict__ W1, const float* __restrict__ b1,
    const float* __restrict__ W2, const float* __restrict__ b2,
    float* __restrict__ dmat, float* __restrict__ rowsum,
    float* __restrict__ colsum)
{
    __shared__ __align__(16) short embs[EPB * ROWP];   // 17.4 KB
    __shared__ __align__(16) short w1t[NPAD * ROWP];   // 30.5 KB, W1 transposed [j][k]
    __shared__ float b1s[NPAD];
    __shared__ float w2s[NPAD];

    const int tid = threadIdx.x;
    const int e0  = blockIdx.x * EPB;

    // Stage W1^T (bf16). j >= 100 padded with zeros; W2 pad = 0 makes pad j's inert.
    for (int idx = tid; idx < NPAD * KDIM; idx += 256) {
        int j = idx >> 7, k = idx & 127;
        float v = (j < 100) ? W1[k * 100 + j] : 0.f;
        w1t[j * ROWP + k] = (short)f2bf(v);
    }
    if (tid < NPAD) {
        b1s[tid] = (tid < 100) ? b1[tid] : 0.f;
        w2s[tid] = (tid < 100) ? W2[tid] : 0.f;
    }

    // Gather 64 emb rows (fp32) -> bf16 LDS. 4 threads per entry, float4 loads.
    {
        int i = tid >> 2, c = tid & 3;
        int r = d_rows[e0 + i];
        const float4* src = (const float4*)(emb + (size_t)r * EMB_DIM);
        for (int u = 0; u < 8; ++u) {
            int f4 = u * 4 + c;              // float4 index 0..31 within the row
            float4 v = src[f4];
            short* dst = &embs[i * ROWP + f4 * 4];
            dst[0] = (short)f2bf(v.x);
            dst[1] = (short)f2bf(v.y);
            dst[2] = (short)f2bf(v.z);
            dst[3] = (short)f2bf(v.w);
        }
    }
    __syncthreads();

    const int lane = tid & 63;
    const int w    = tid >> 6;      // wave id: 16-entry stripe
    const int col  = lane & 15;
    const int quad = lane >> 4;

    // A fragments (entry stripe), reused across all 7 j-tiles.
    // A layout: A[m = lane&15][k = quad*8 + j]  (m89/m91-verified)
    const short* ap = &embs[(w * 16 + col) * ROWP + quad * 8];
    short8 a0 = *(const short8*)(ap);
    short8 a1 = *(const short8*)(ap + 32);
    short8 a2 = *(const short8*)(ap + 64);
    short8 a3 = *(const short8*)(ap + 96);

    float s0 = 0.f, s1 = 0.f, s2 = 0.f, s3 = 0.f;  // per-reg partial h.W2 dots
    for (int jt = 0; jt < 7; ++jt) {
        // B layout mirrors A: B[k = quad*8 + j][n = lane&15]; W1T[j][k] rows
        // make the 8 k's contiguous -> ds_read_b128.
        const short* bp = &w1t[(jt * 16 + col) * ROWP + quad * 8];
        short8 bv0 = *(const short8*)(bp);
        short8 bv1 = *(const short8*)(bp + 32);
        short8 bv2 = *(const short8*)(bp + 64);
        short8 bv3 = *(const short8*)(bp + 96);

        float4v acc = {0.f, 0.f, 0.f, 0.f};
        acc = __builtin_amdgcn_mfma_f32_16x16x32_bf16(a0, bv0, acc, 0, 0, 0);
        acc = __builtin_amdgcn_mfma_f32_16x16x32_bf16(a1, bv1, acc, 0, 0, 0);
        acc = __builtin_amdgcn_mfma_f32_16x16x32_bf16(a2, bv2, acc, 0, 0, 0);
        acc = __builtin_amdgcn_mfma_f32_16x16x32_bf16(a3, bv3, acc, 0, 0, 0);

        // D layout: row(entry) = quad*4 + reg, col(j) = lane&15
        float b1v = b1s[jt * 16 + col];
        float w2v = w2s[jt * 16 + col];
        float h;
        h = acc[0] + b1v; h = h > 0.f ? h : 0.f; s0 += h * w2v;
        h = acc[1] + b1v; h = h > 0.f ? h : 0.f; s1 += h * w2v;
        h = acc[2] + b1v; h = h > 0.f ? h : 0.f; s2 += h * w2v;
        h = acc[3] + b1v; h = h > 0.f ? h : 0.f; s3 += h * w2v;
    }
    // Sum over the 16 j-columns held by the 16 lanes of this quad-group.
    for (int m = 1; m < 16; m <<= 1) {
        s0 += __shfl_xor(s0, m, 64);
        s1 += __shfl_xor(s1, m, 64);
        s2 += __shfl_xor(s2, m, 64);
        s3 += __shfl_xor(s3, m, 64);
    }
    if (col < 4) {  // lanes 0..3 of each quad-group handle entries quad*4 + 0..3
        float sv = (col == 0) ? s0 : (col == 1) ? s1 : (col == 2) ? s2 : s3;
        int e = e0 + w * 16 + quad * 4 + col;
        float tdv = sv + b2[0];
        tdv = tdv > 0.f ? tdv : 0.f;
        float ft = tdv * d_freqs[e];
        int r = d_rows[e];
        int c = d_cols[e];
        atomicAdd(&dmat[(size_t)r * BATCH + c], ft);
        atomicAdd(&rowsum[r], ft);
        atomicAdd(&colsum[c], ft);
    }
}

__global__ void total_kernel(const float* __restrict__ colsum,
                             float* __restrict__ total) {
    __shared__ float red[256];
    int t = threadIdx.x;
    red[t] = colsum[t];
    __syncthreads();
    for (int s = 128; s > 0; s >>= 1) {
        if (t < s) red[t] += red[t + s];
        __syncthreads();
    }
    if (t == 0) total[0] = red[0];
}

// rel[b] = sum_e q_vals[e] * dir_d[q_rows[e], q_cols[e]] — dir_d evaluated
// only at the 2048 q positions.
__global__ void rel_kernel(const int* __restrict__ q_rows,
                           const int* __restrict__ q_cols,
                           const float* __restrict__ q_vals,
                           const float* __restrict__ dmat,
                           const float* __restrict__ rowsum,
                           const float* __restrict__ colsum,
                           const float* __restrict__ total,
                           const float* __restrict__ mu_p,
                           float* __restrict__ rel)
{
    int e = blockIdx.x * blockDim.x + threadIdx.x;
    if (e >= NNZ_Q) return;
    int v = q_rows[e], b = q_cols[e];
    float mu = mu_p[0];
    float dval = dmat[(size_t)v * BATCH + b];
    float cf = rowsum[v] / total[0];
    float dir = log1pf(dval / (1.f + mu * cf)) + logf(mu / (colsum[b] + mu));
    atomicAdd(&rel[b], q_vals[e] * dir);
}

extern "C" void kernel_launch(void* const* d_in, const int* in_sizes, int n_in,
                              void* d_out, int out_size, void* d_ws, size_t ws_size,
                              hipStream_t stream)
{
    const int*   q_rows  = (const int*)d_in[0];
    const int*   q_cols  = (const int*)d_in[1];
    const float* q_vals  = (const float*)d_in[2];
    const int*   d_rows  = (const int*)d_in[3];
    const int*   d_cols  = (const int*)d_in[4];
    const float* d_freqs = (const float*)d_in[5];
    const float* emb     = (const float*)d_in[6];
    const float* W1      = (const float*)d_in[7];
    const float* b1      = (const float*)d_in[8];
    const float* W2      = (const float*)d_in[9];
    const float* b2      = (const float*)d_in[10];
    const float* mu      = (const float*)d_in[11];

    float* rel  = (float*)d_out;        // output 0: rel [256]
    float* dmat = rel + BATCH;          // output 1: d [100001, 256]

    float* rowsum = (float*)d_ws;          // [100001] (padded to 100352)
    float* colsum = rowsum + 100352;       // [256]
    float* total  = colsum + 256;          // [1]

    // d_out and d_ws are re-poisoned to 0xAA before every timed launch.
    hipMemsetAsync(d_out, 0, (size_t)out_size * sizeof(float), stream);
    hipMemsetAsync(d_ws, 0, (size_t)(100352 + 256 + 16) * sizeof(float), stream);

    mlp_scatter_kernel<<<NNZ_D / EPB, 256, 0, stream>>>(
        d_rows, d_cols, d_freqs, emb, W1, b1, W2, b2, dmat, rowsum, colsum);
    total_kernel<<<1, 256, 0, stream>>>(colsum, total);
    rel_kernel<<<NNZ_Q / 256, 256, 0, stream>>>(
        q_rows, q_cols, q_vals, dmat, rowsum, colsum, total, mu, rel);
}

// Round 2
// 221.022 us; speedup vs baseline: 2.1481x; 2.1481x over previous
//
#include <hip/hip_runtime.h>
#include <stdint.h>

// Problem constants (fixed by the reference).
#define VOCAB_P1 100001
#define EMB_DIM  128
#define BATCH    256
#define NNZ_Q    2048
#define NNZ_D    262144

#define NPAD 112   // hidden dim 100 padded to 7 MFMA tiles of 16
#define ROWP 136   // w1t LDS row stride in shorts: 128 + 8 (16B-aligned, odd 16B-unit count)
#define NGRP 6251  // ceil(100001 / 16) row-groups for the MLP

typedef __attribute__((ext_vector_type(8))) short  short8;   // 8 bf16 = 4 VGPRs
typedef __attribute__((ext_vector_type(4))) float  float4v;  // MFMA acc

__device__ __forceinline__ unsigned short f2bf(float f) {
    union { float f; unsigned u; } v; v.f = f;
    unsigned u = v.u;
    u += 0x7fffu + ((u >> 16) & 1u);     // RNE float -> bf16
    return (unsigned short)(u >> 16);
}

__device__ __forceinline__ short8 cvt8(float4 a, float4 b) {
    short8 r;
    r[0] = (short)f2bf(a.x); r[1] = (short)f2bf(a.y);
    r[2] = (short)f2bf(a.z); r[3] = (short)f2bf(a.w);
    r[4] = (short)f2bf(b.x); r[5] = (short)f2bf(b.y);
    r[6] = (short)f2bf(b.z); r[7] = (short)f2bf(b.w);
    return r;
}

// Per-UNIQUE-vocab-row MLP: tdv[r] = relu(relu(emb[r] @ W1 + b1) @ W2 + b2).
// emb is STREAMED coalesced (no gather); A-fragments come straight from
// global (16B/lane), B (W1^T bf16) staged once per block in LDS.
__global__ __launch_bounds__(256) void mlp_tdv_kernel(
    const float* __restrict__ emb, const float* __restrict__ W1,
    const float* __restrict__ b1, const float* __restrict__ W2,
    const float* __restrict__ b2, float* __restrict__ tdvtab)
{
    __shared__ __align__(16) short w1t[NPAD * ROWP];   // 30.5 KB
    __shared__ float b1s[NPAD];
    __shared__ float w2s[NPAD];

    const int tid = threadIdx.x;

    // Zero-fill (pad rows j=100..111 must be 0 so relu(0+0)*0 stays finite).
    int* w1i = (int*)w1t;
    for (int i = tid; i < NPAD * ROWP / 2; i += 256) w1i[i] = 0;
    __syncthreads();
    // Coalesced W1 read: flat f = k*100 + j (W1 is [128,100] row-major).
    for (int f = tid; f < EMB_DIM * 100; f += 256) {
        int k = f / 100, j = f - k * 100;
        w1t[j * ROWP + k] = (short)f2bf(W1[f]);
    }
    if (tid < NPAD) {
        b1s[tid] = (tid < 100) ? b1[tid] : 0.f;
        w2s[tid] = (tid < 100) ? W2[tid] : 0.f;
    }
    __syncthreads();

    const int lane = tid & 63;
    const int w    = tid >> 6;
    const int col  = lane & 15;
    const int quad = lane >> 4;
    const float b2v = b2[0];
    const int nw = gridDim.x * 4;

    for (int grp = blockIdx.x * 4 + w; grp < NGRP; grp += nw) {
        int r  = grp * 16 + col;
        int rr = (r <= VOCAB_P1 - 1) ? r : (VOCAB_P1 - 1);   // clamp OOB reads
        const float* rp = emb + (size_t)rr * EMB_DIM + quad * 8;
        // A layout: A[m=lane&15][k=quad*8+j], fragment f covers k0=f*32.
        float4 u0 = *(const float4*)(rp);
        float4 u1 = *(const float4*)(rp + 4);
        float4 u2 = *(const float4*)(rp + 32);
        float4 u3 = *(const float4*)(rp + 36);
        float4 u4 = *(const float4*)(rp + 64);
        float4 u5 = *(const float4*)(rp + 68);
        float4 u6 = *(const float4*)(rp + 96);
        float4 u7 = *(const float4*)(rp + 100);
        short8 a0 = cvt8(u0, u1), a1 = cvt8(u2, u3);
        short8 a2 = cvt8(u4, u5), a3 = cvt8(u6, u7);

        float s0 = 0.f, s1 = 0.f, s2 = 0.f, s3 = 0.f;
        for (int jt = 0; jt < 7; ++jt) {
            const short* bp = &w1t[(jt * 16 + col) * ROWP + quad * 8];
            short8 bv0 = *(const short8*)(bp);
            short8 bv1 = *(const short8*)(bp + 32);
            short8 bv2 = *(const short8*)(bp + 64);
            short8 bv3 = *(const short8*)(bp + 96);

            float4v acc = {0.f, 0.f, 0.f, 0.f};
            acc = __builtin_amdgcn_mfma_f32_16x16x32_bf16(a0, bv0, acc, 0, 0, 0);
            acc = __builtin_amdgcn_mfma_f32_16x16x32_bf16(a1, bv1, acc, 0, 0, 0);
            acc = __builtin_amdgcn_mfma_f32_16x16x32_bf16(a2, bv2, acc, 0, 0, 0);
            acc = __builtin_amdgcn_mfma_f32_16x16x32_bf16(a3, bv3, acc, 0, 0, 0);

            // D layout: row = quad*4 + reg, col(j) = lane&15
            float b1v = b1s[jt * 16 + col];
            float w2v = w2s[jt * 16 + col];
            float h;
            h = acc[0] + b1v; h = h > 0.f ? h : 0.f; s0 += h * w2v;
            h = acc[1] + b1v; h = h > 0.f ? h : 0.f; s1 += h * w2v;
            h = acc[2] + b1v; h = h > 0.f ? h : 0.f; s2 += h * w2v;
            h = acc[3] + b1v; h = h > 0.f ? h : 0.f; s3 += h * w2v;
        }
        for (int m = 1; m < 16; m <<= 1) {
            s0 += __shfl_xor(s0, m, 64);
            s1 += __shfl_xor(s1, m, 64);
            s2 += __shfl_xor(s2, m, 64);
            s3 += __shfl_xor(s3, m, 64);
        }
        if (col < 4) {
            float sv = (col == 0) ? s0 : (col == 1) ? s1 : (col == 2) ? s2 : s3;
            int row = grp * 16 + quad * 4 + col;
            if (row < VOCAB_P1) {
                float tdv = sv + b2v;
                tdvtab[row] = tdv > 0.f ? tdv : 0.f;
            }
        }
    }
}

// Per-entry scatter: ft = tdv[row] * freq -> dmat / rowsum / colsum.
// colsum aggregated per-block in LDS (256 slots) to cut same-address
// global atomic contention 4x.
__global__ __launch_bounds__(256) void scatter_kernel(
    const int* __restrict__ d_rows, const int* __restrict__ d_cols,
    const float* __restrict__ d_freqs, const float* __restrict__ tdvtab,
    float* __restrict__ dmat, float* __restrict__ rowsum,
    float* __restrict__ colsum)
{
    __shared__ float cs[BATCH];
    const int tid = threadIdx.x;
    cs[tid] = 0.f;
    __syncthreads();

    int g = blockIdx.x * 256 + tid;              // int4 index, 65536 total
    int4   r4 = ((const int4*)d_rows)[g];
    int4   c4 = ((const int4*)d_cols)[g];
    float4 f4 = ((const float4*)d_freqs)[g];

    float t0 = tdvtab[r4.x], t1 = tdvtab[r4.y];
    float t2 = tdvtab[r4.z], t3 = tdvtab[r4.w];
    float ft0 = t0 * f4.x, ft1 = t1 * f4.y, ft2 = t2 * f4.z, ft3 = t3 * f4.w;

    atomicAdd(&dmat[(size_t)r4.x * BATCH + c4.x], ft0);
    atomicAdd(&dmat[(size_t)r4.y * BATCH + c4.y], ft1);
    atomicAdd(&dmat[(size_t)r4.z * BATCH + c4.z], ft2);
    atomicAdd(&dmat[(size_t)r4.w * BATCH + c4.w], ft3);
    atomicAdd(&rowsum[r4.x], ft0);
    atomicAdd(&rowsum[r4.y], ft1);
    atomicAdd(&rowsum[r4.z], ft2);
    atomicAdd(&rowsum[r4.w], ft3);
    atomicAdd(&cs[c4.x], ft0);
    atomicAdd(&cs[c4.y], ft1);
    atomicAdd(&cs[c4.z], ft2);
    atomicAdd(&cs[c4.w], ft3);

    __syncthreads();
    atomicAdd(&colsum[tid], cs[tid]);
}

// rel[b] = sum_e q_vals[e] * dir_d[q_rows[e], q_cols[e]] — dir_d evaluated
// at the 2048 q positions only. Each block redundantly reduces total(=sum colsum).
__global__ __launch_bounds__(256) void rel_kernel(
    const int* __restrict__ q_rows, const int* __restrict__ q_cols,
    const float* __restrict__ q_vals, const float* __restrict__ dmat,
    const float* __restrict__ rowsum, const float* __restrict__ colsum,
    const float* __restrict__ mu_p, float* __restrict__ rel)
{
    __shared__ float csh[BATCH];
    __shared__ float red[BATCH];
    const int tid = threadIdx.x;
    float c = colsum[tid];
    csh[tid] = c;
    red[tid] = c;
    __syncthreads();
    for (int s = 128; s > 0; s >>= 1) {
        if (tid < s) red[tid] += red[tid + s];
        __syncthreads();
    }
    float tot = red[0];
    float mu  = mu_p[0];

    int e = blockIdx.x * 256 + tid;              // 8 blocks x 256 = 2048
    int v = q_rows[e], b = q_cols[e];
    float dval = dmat[(size_t)v * BATCH + b];
    float cf   = rowsum[v] / tot;
    float dir  = log1pf(dval / (1.f + mu * cf)) + logf(mu / (csh[b] + mu));
    atomicAdd(&rel[b], q_vals[e] * dir);
}

extern "C" void kernel_launch(void* const* d_in, const int* in_sizes, int n_in,
                              void* d_out, int out_size, void* d_ws, size_t ws_size,
                              hipStream_t stream)
{
    const int*   q_rows  = (const int*)d_in[0];
    const int*   q_cols  = (const int*)d_in[1];
    const float* q_vals  = (const float*)d_in[2];
    const int*   d_rows  = (const int*)d_in[3];
    const int*   d_cols  = (const int*)d_in[4];
    const float* d_freqs = (const float*)d_in[5];
    const float* emb     = (const float*)d_in[6];
    const float* W1      = (const float*)d_in[7];
    const float* b1      = (const float*)d_in[8];
    const float* W2      = (const float*)d_in[9];
    const float* b2      = (const float*)d_in[10];
    const float* mu      = (const float*)d_in[11];

    float* rel  = (float*)d_out;          // output 0: rel [256]
    float* dmat = rel + BATCH;            // output 1: d [100001, 256]

    float* rowsum = (float*)d_ws;         // [100352]
    float* colsum = rowsum + 100352;      // [256]
    float* tdvtab = colsum + 256;         // [100001]

    hipMemsetAsync(d_out, 0, (size_t)out_size * sizeof(float), stream);
    hipMemsetAsync(d_ws, 0, (size_t)(100352 + 256) * sizeof(float), stream);

    mlp_tdv_kernel<<<1024, 256, 0, stream>>>(emb, W1, b1, W2, b2, tdvtab);
    scatter_kernel<<<NNZ_D / 1024, 256, 0, stream>>>(
        d_rows, d_cols, d_freqs, tdvtab, dmat, rowsum, colsum);
    rel_kernel<<<NNZ_Q / 256, 256, 0, stream>>>(
        q_rows, q_cols, q_vals, dmat, rowsum, colsum, mu, rel);
}